// Round 2
// baseline (370.114 us; speedup 1.0000x reference)
//
#include <hip/hip_runtime.h>
#include <cstdint>
#include <math.h>

#define Nn   16
#define Cc   64
#define Ww   512
#define Hh   512
#define RED  64
#define OUTW 128

// Monotone float<->uint32 encoding: f1 < f2  <=>  enc(f1) < enc(f2) (unsigned)
__device__ __forceinline__ unsigned enc_f32(float f) {
    unsigned b = __float_as_uint(f);
    return (b & 0x80000000u) ? ~b : (b | 0x80000000u);
}
__device__ __forceinline__ float dec_f32(unsigned u) {
    unsigned b = (u & 0x80000000u) ? (u & 0x7FFFFFFFu) : ~u;
    return __uint_as_float(b);
}

// ---------------------------------------------------------------------------
// Kernel 0: init pooled_u[16*512] = 0  (0 is below enc() of any finite float)
// ---------------------------------------------------------------------------
__global__ void init_kernel(unsigned* __restrict__ pu) {
    pu[blockIdx.x * 256 + threadIdx.x] = 0u;
}

// ---------------------------------------------------------------------------
// Kernel 1: per-(n,c)-plane pooling. Block b=(n,c) streams its contiguous 1MB
// plane; wave wv owns rows [wv*128, wv*128+128) -> contiguous 256KB stream.
// Per row: 8-elem per-lane max + 6-step shfl_xor butterfly; 2 rows in flight.
// Publish: atomicMax(pooled_u[n][w], enc(rowmax)) over c.
// ---------------------------------------------------------------------------
__global__ void __launch_bounds__(256) pool_kernel(const float* __restrict__ x,
                                                   unsigned* __restrict__ pu) {
    const int b = blockIdx.x;                 // n*64 + c
    const int n = b >> 6;
    const float* plane = x + (size_t)b * (Ww * Hh);
    const int wv   = threadIdx.x >> 6;
    const int lane = threadIdx.x & 63;
    const int rbase = wv * 128;

    #pragma unroll 2
    for (int it = 0; it < 64; ++it) {
        const int r0 = rbase + it * 2;
        const float4* p0 = reinterpret_cast<const float4*>(plane + (size_t)r0 * Hh);
        const float4* p1 = reinterpret_cast<const float4*>(plane + (size_t)(r0 + 1) * Hh);
        const float4 a0 = p0[lane], b0 = p0[lane + 64];
        const float4 a1 = p1[lane], b1 = p1[lane + 64];
        float m0 = fmaxf(fmaxf(fmaxf(a0.x, a0.y), fmaxf(a0.z, a0.w)),
                         fmaxf(fmaxf(b0.x, b0.y), fmaxf(b0.z, b0.w)));
        float m1 = fmaxf(fmaxf(fmaxf(a1.x, a1.y), fmaxf(a1.z, a1.w)),
                         fmaxf(fmaxf(b1.x, b1.y), fmaxf(b1.z, b1.w)));
        #pragma unroll
        for (int off = 1; off < 64; off <<= 1) {
            m0 = fmaxf(m0, __shfl_xor(m0, off, 64));
            m1 = fmaxf(m1, __shfl_xor(m1, off, 64));
        }
        if (lane == 0) atomicMax(&pu[n * Ww + r0],     enc_f32(m0));
        if (lane == 1) atomicMax(&pu[n * Ww + r0 + 1], enc_f32(m1));
    }
}

// ---------------------------------------------------------------------------
// Kernel 2: MLP + BatchNorm(batch stats) + ReLU + logits + top-128 select.
// 16 blocks (one per batch row). Softmax skipped (monotone). Tie-break matches
// jax.lax.top_k: (value desc, index asc). Rank-select emits sorted indices.
// ---------------------------------------------------------------------------
__global__ void __launch_bounds__(512) mlp_topk_kernel(
    const unsigned* __restrict__ pu,    // [16][512] encoded
    const float* __restrict__ w1,       // [64][512]
    const float* __restrict__ b1,       // [64]
    const float* __restrict__ gamma,    // [64]
    const float* __restrict__ beta,     // [64]
    const float* __restrict__ w2,       // [512][64]
    const float* __restrict__ b2,       // [512]
    int* __restrict__ idx_out)          // [16][128]
{
    const int row = blockIdx.x;
    const int tid = threadIdx.x;

    __shared__ float pooled_t[Ww][Nn + 1];   // [w][n], padded
    __shared__ float hbn_t[RED][Nn + 1];     // [r][n]
    __shared__ float mu_s[RED], is_s[RED];
    __shared__ float logits_row[Ww];
    __shared__ unsigned long long sel_mask[Ww / 64];

    for (int i = tid; i < Nn * Ww; i += 512) {
        const int n = i >> 9, k = i & 511;
        pooled_t[k][n] = dec_f32(pu[i]);
    }
    __syncthreads();

    // h[n][r] = pooled[n,:] . w1[r,:] + b1[r]
    float hv[2];
    int hn[2], hr[2];
    #pragma unroll
    for (int e = 0; e < 2; ++e) {
        const int item = e * 512 + tid;
        const int n = item & 15, r = item >> 4;
        hn[e] = n; hr[e] = r;
        float acc = b1[r];
        for (int k = 0; k < Ww; ++k)
            acc += pooled_t[k][n] * w1[r * Ww + k];
        hv[e] = acc;
    }
    #pragma unroll
    for (int e = 0; e < 2; ++e) hbn_t[hr[e]][hn[e]] = hv[e];
    __syncthreads();

    if (tid < RED) {
        float s = 0.f, s2 = 0.f;
        #pragma unroll
        for (int n = 0; n < Nn; ++n) { const float v = hbn_t[tid][n]; s += v; s2 += v * v; }
        const float mu  = s  * (1.f / Nn);
        const float var = s2 * (1.f / Nn) - mu * mu;
        mu_s[tid] = mu;
        is_s[tid] = 1.f / sqrtf(var + 1e-5f);
    }
    __syncthreads();

    #pragma unroll
    for (int e = 0; e < 2; ++e) {
        const int r = hr[e], n = hn[e];
        const float v = gamma[r] * (hv[e] - mu_s[r]) * is_s[r] + beta[r];
        hbn_t[r][n] = fmaxf(v, 0.f);
    }
    __syncthreads();

    {
        const int w = tid;
        float acc = b2[w];
        #pragma unroll
        for (int r = 0; r < RED; ++r)
            acc += hbn_t[r][row] * w2[w * RED + r];
        logits_row[w] = acc;
    }
    __syncthreads();

    {
        const int w = tid;
        const float v = logits_row[w];
        int rank = 0;
        for (int ww = 0; ww < Ww; ++ww) {
            const float u = logits_row[ww];
            rank += (u > v || (u == v && ww < w)) ? 1 : 0;
        }
        const bool sel = (rank < OUTW);
        const unsigned long long m = __ballot(sel);
        if ((tid & 63) == 0) sel_mask[tid >> 6] = m;
        __syncthreads();
        if (sel) {
            int pos = 0;
            #pragma unroll
            for (int bb = 0; bb < (Ww / 64); ++bb)
                if (bb < (w >> 6)) pos += __popcll(sel_mask[bb]);
            pos += __popcll(sel_mask[w >> 6] & ((1ULL << (w & 63)) - 1ULL));
            idx_out[row * OUTW + pos] = w;
        }
    }
}

// ---------------------------------------------------------------------------
// Kernel 3: out[n][c][j][h] = x[n][c][idx[n][j]][h]
// Block b=(n,c): reads 128 sorted rows ascending within one contiguous 1MB
// plane; writes one fully contiguous 256KB slab.
// ---------------------------------------------------------------------------
__global__ void __launch_bounds__(256) gather_kernel(const float* __restrict__ x,
                                                     const int* __restrict__ idx,
                                                     float* __restrict__ out) {
    const int b = blockIdx.x;                 // n*64 + c
    const int n = b >> 6;
    const int tid = threadIdx.x;
    __shared__ int sidx[OUTW];
    if (tid < OUTW) sidx[tid] = idx[n * OUTW + tid];
    __syncthreads();
    const float* src = x   + (size_t)b * (Ww * Hh);
    float*       dst = out + (size_t)b * (OUTW * Hh);
    #pragma unroll 4
    for (int i = tid; i < OUTW * (Hh / 4); i += 256) {
        const int j = i >> 7;                 // output width slot
        const int f = i & 127;                // float4 within row
        const float4 v = *reinterpret_cast<const float4*>(src + (size_t)sidx[j] * Hh + f * 4);
        *reinterpret_cast<float4*>(dst + (size_t)j * Hh + f * 4) = v;
    }
}

// ---------------------------------------------------------------------------
extern "C" void kernel_launch(void* const* d_in, const int* in_sizes, int n_in,
                              void* d_out, int out_size, void* d_ws, size_t ws_size,
                              hipStream_t stream) {
    const float* x     = (const float*)d_in[0];
    const float* w1    = (const float*)d_in[1];
    const float* b1    = (const float*)d_in[2];
    const float* gamma = (const float*)d_in[3];
    const float* beta  = (const float*)d_in[4];
    const float* w2    = (const float*)d_in[5];
    const float* b2    = (const float*)d_in[6];
    float* out = (float*)d_out;

    unsigned* pu  = (unsigned*)d_ws;                                  // 16*512 u32 = 32 KB
    int*      idx = (int*)((char*)d_ws + Nn * Ww * sizeof(unsigned)); // 16*128 i32 =  8 KB

    init_kernel<<<(Nn * Ww) / 256, 256, 0, stream>>>(pu);
    pool_kernel<<<Nn * Cc, 256, 0, stream>>>(x, pu);
    mlp_topk_kernel<<<Nn, 512, 0, stream>>>(pu, w1, b1, gamma, beta, w2, b2, idx);
    gather_kernel<<<Nn * Cc, 256, 0, stream>>>(x, idx, out);
}

// Round 3
// 344.971 us; speedup vs baseline: 1.0729x; 1.0729x over previous
//
#include <hip/hip_runtime.h>
#include <cstdint>
#include <math.h>

#define Nn   16
#define Cc   64
#define Ww   512
#define Hh   512
#define RED  64
#define OUTW 128

// ---------------------------------------------------------------------------
// Kernel 1: pooled[n][w] = max over (c,h) of x[n][c][w][h]
// Block b = (n, w-quad): 4 waves, wave r owns row w = q*4+r.
// Per c-step the block reads 8 KB contiguous (4 rows x 2 KB); each lane keeps
// 8 independent max accumulators across all 64 c's; ONE 6-step butterfly at
// the end per wave. No atomics, no init pass.
// ---------------------------------------------------------------------------
__global__ void __launch_bounds__(256) pool_kernel(const float* __restrict__ x,
                                                   float* __restrict__ pooled) {
    const int b = blockIdx.x;            // n*128 + q
    const int n = b >> 7;
    const int q = b & 127;
    const int r = threadIdx.x >> 6;      // wave id = row within quad
    const int lane = threadIdx.x & 63;
    const int w = q * 4 + r;
    const float* base = x + ((size_t)n * Cc * Ww + w) * Hh + lane * 8;

    float m0 = -INFINITY, m1 = -INFINITY, m2 = -INFINITY, m3 = -INFINITY;
    float m4 = -INFINITY, m5 = -INFINITY, m6 = -INFINITY, m7 = -INFINITY;
    #pragma unroll 4
    for (int c = 0; c < Cc; ++c) {
        const float* p = base + (size_t)c * (Ww * Hh);
        const float4 v0 = *reinterpret_cast<const float4*>(p);
        const float4 v1 = *reinterpret_cast<const float4*>(p + 4);
        m0 = fmaxf(m0, v0.x); m1 = fmaxf(m1, v0.y);
        m2 = fmaxf(m2, v0.z); m3 = fmaxf(m3, v0.w);
        m4 = fmaxf(m4, v1.x); m5 = fmaxf(m5, v1.y);
        m6 = fmaxf(m6, v1.z); m7 = fmaxf(m7, v1.w);
    }
    float m = fmaxf(fmaxf(fmaxf(m0, m1), fmaxf(m2, m3)),
                    fmaxf(fmaxf(m4, m5), fmaxf(m6, m7)));
    #pragma unroll
    for (int off = 1; off < 64; off <<= 1)
        m = fmaxf(m, __shfl_xor(m, off, 64));
    if (lane == 0) pooled[n * Ww + w] = m;
}

// ---------------------------------------------------------------------------
// Kernel 2: MLP + BatchNorm(batch stats) + ReLU + logits + top-128 select.
// 16 blocks (one per batch row). Softmax skipped (monotone). Tie-break matches
// jax.lax.top_k: (value desc, index asc). Rank-select emits sorted indices.
// ---------------------------------------------------------------------------
__global__ void __launch_bounds__(512) mlp_topk_kernel(
    const float* __restrict__ pooled,   // [16][512]
    const float* __restrict__ w1,       // [64][512]
    const float* __restrict__ b1,       // [64]
    const float* __restrict__ gamma,    // [64]
    const float* __restrict__ beta,     // [64]
    const float* __restrict__ w2,       // [512][64]
    const float* __restrict__ b2,       // [512]
    int* __restrict__ idx_out)          // [16][128]
{
    const int row = blockIdx.x;
    const int tid = threadIdx.x;

    __shared__ float pooled_t[Ww][Nn + 1];   // [w][n], padded
    __shared__ float hbn_t[RED][Nn + 1];     // [r][n]
    __shared__ float mu_s[RED], is_s[RED];
    __shared__ float logits_row[Ww];
    __shared__ unsigned long long sel_mask[Ww / 64];

    for (int i = tid; i < Nn * Ww; i += 512) {
        const int n = i >> 9, k = i & 511;
        pooled_t[k][n] = pooled[i];
    }
    __syncthreads();

    // h[n][r] = pooled[n,:] . w1[r,:] + b1[r]
    float hv[2];
    int hn[2], hr[2];
    #pragma unroll
    for (int e = 0; e < 2; ++e) {
        const int item = e * 512 + tid;
        const int n = item & 15, r = item >> 4;
        hn[e] = n; hr[e] = r;
        float acc = b1[r];
        for (int k = 0; k < Ww; ++k)
            acc += pooled_t[k][n] * w1[r * Ww + k];
        hv[e] = acc;
    }
    #pragma unroll
    for (int e = 0; e < 2; ++e) hbn_t[hr[e]][hn[e]] = hv[e];
    __syncthreads();

    if (tid < RED) {
        float s = 0.f, s2 = 0.f;
        #pragma unroll
        for (int n = 0; n < Nn; ++n) { const float v = hbn_t[tid][n]; s += v; s2 += v * v; }
        const float mu  = s  * (1.f / Nn);
        const float var = s2 * (1.f / Nn) - mu * mu;
        mu_s[tid] = mu;
        is_s[tid] = 1.f / sqrtf(var + 1e-5f);
    }
    __syncthreads();

    #pragma unroll
    for (int e = 0; e < 2; ++e) {
        const int r = hr[e], n = hn[e];
        const float v = gamma[r] * (hv[e] - mu_s[r]) * is_s[r] + beta[r];
        hbn_t[r][n] = fmaxf(v, 0.f);
    }
    __syncthreads();

    {
        const int w = tid;
        float acc = b2[w];
        #pragma unroll
        for (int r = 0; r < RED; ++r)
            acc += hbn_t[r][row] * w2[w * RED + r];
        logits_row[w] = acc;
    }
    __syncthreads();

    {
        const int w = tid;
        const float v = logits_row[w];
        int rank = 0;
        for (int ww = 0; ww < Ww; ++ww) {
            const float u = logits_row[ww];
            rank += (u > v || (u == v && ww < w)) ? 1 : 0;
        }
        const bool sel = (rank < OUTW);
        const unsigned long long m = __ballot(sel);
        if ((tid & 63) == 0) sel_mask[tid >> 6] = m;
        __syncthreads();
        if (sel) {
            int pos = 0;
            #pragma unroll
            for (int bb = 0; bb < (Ww / 64); ++bb)
                if (bb < (w >> 6)) pos += __popcll(sel_mask[bb]);
            pos += __popcll(sel_mask[w >> 6] & ((1ULL << (w & 63)) - 1ULL));
            idx_out[row * OUTW + pos] = w;
        }
    }
}

// ---------------------------------------------------------------------------
// Kernel 3: out[n][c][j][h] = x[n][c][idx[n][j]][h]
// Block b=(n,c): reads 128 sorted rows ascending within one contiguous 1MB
// plane; writes one fully contiguous 256KB slab.
// ---------------------------------------------------------------------------
__global__ void __launch_bounds__(256) gather_kernel(const float* __restrict__ x,
                                                     const int* __restrict__ idx,
                                                     float* __restrict__ out) {
    const int b = blockIdx.x;                 // n*64 + c
    const int n = b >> 6;
    const int tid = threadIdx.x;
    __shared__ int sidx[OUTW];
    if (tid < OUTW) sidx[tid] = idx[n * OUTW + tid];
    __syncthreads();
    const float* src = x   + (size_t)b * (Ww * Hh);
    float*       dst = out + (size_t)b * (OUTW * Hh);
    #pragma unroll 4
    for (int i = tid; i < OUTW * (Hh / 4); i += 256) {
        const int j = i >> 7;                 // output width slot
        const int f = i & 127;                // float4 within row
        const float4 v = *reinterpret_cast<const float4*>(src + (size_t)sidx[j] * Hh + f * 4);
        *reinterpret_cast<float4*>(dst + (size_t)j * Hh + f * 4) = v;
    }
}

// ---------------------------------------------------------------------------
extern "C" void kernel_launch(void* const* d_in, const int* in_sizes, int n_in,
                              void* d_out, int out_size, void* d_ws, size_t ws_size,
                              hipStream_t stream) {
    const float* x     = (const float*)d_in[0];
    const float* w1    = (const float*)d_in[1];
    const float* b1    = (const float*)d_in[2];
    const float* gamma = (const float*)d_in[3];
    const float* beta  = (const float*)d_in[4];
    const float* w2    = (const float*)d_in[5];
    const float* b2    = (const float*)d_in[6];
    float* out = (float*)d_out;

    float* pooled = (float*)d_ws;                                   // 16*512 f32 = 32 KB
    int*   idx    = (int*)((char*)d_ws + Nn * Ww * sizeof(float));  // 16*128 i32 =  8 KB

    pool_kernel<<<Nn * (Ww / 4), 256, 0, stream>>>(x, pooled);
    mlp_topk_kernel<<<Nn, 512, 0, stream>>>(pooled, w1, b1, gamma, beta, w2, b2, idx);
    gather_kernel<<<Nn * Cc, 256, 0, stream>>>(x, idx, out);
}

// Round 4
// 322.983 us; speedup vs baseline: 1.1459x; 1.0681x over previous
//
#include <hip/hip_runtime.h>
#include <cstdint>
#include <math.h>

#define Nn   16
#define Cc   64
#define Ww   512
#define Hh   512
#define RED  64
#define OUTW 128

// ---------------------------------------------------------------------------
// Kernel 1: pooled[n][w] = max over (c,h) of x[n][c][w][h]
// Block b = (n, w-quad): 4 waves, wave r owns row w = q*4+r. Per c-step the
// block reads 8 KB contiguous; 8 independent accumulators per lane; one
// butterfly at the end. (R3 structure — tied best.)
// ---------------------------------------------------------------------------
__global__ void __launch_bounds__(256) pool_kernel(const float* __restrict__ x,
                                                   float* __restrict__ pooled) {
    const int b = blockIdx.x;            // n*128 + q
    const int n = b >> 7;
    const int q = b & 127;
    const int r = threadIdx.x >> 6;
    const int lane = threadIdx.x & 63;
    const int w = q * 4 + r;
    const float* base = x + ((size_t)n * Cc * Ww + w) * Hh + lane * 8;

    float m0 = -INFINITY, m1 = -INFINITY, m2 = -INFINITY, m3 = -INFINITY;
    float m4 = -INFINITY, m5 = -INFINITY, m6 = -INFINITY, m7 = -INFINITY;
    #pragma unroll 4
    for (int c = 0; c < Cc; ++c) {
        const float* p = base + (size_t)c * (Ww * Hh);
        const float4 v0 = *reinterpret_cast<const float4*>(p);
        const float4 v1 = *reinterpret_cast<const float4*>(p + 4);
        m0 = fmaxf(m0, v0.x); m1 = fmaxf(m1, v0.y);
        m2 = fmaxf(m2, v0.z); m3 = fmaxf(m3, v0.w);
        m4 = fmaxf(m4, v1.x); m5 = fmaxf(m5, v1.y);
        m6 = fmaxf(m6, v1.z); m7 = fmaxf(m7, v1.w);
    }
    float m = fmaxf(fmaxf(fmaxf(m0, m1), fmaxf(m2, m3)),
                    fmaxf(fmaxf(m4, m5), fmaxf(m6, m7)));
    #pragma unroll
    for (int off = 1; off < 64; off <<= 1)
        m = fmaxf(m, __shfl_xor(m, off, 64));
    if (lane == 0) pooled[n * Ww + w] = m;
}

// ---------------------------------------------------------------------------
// Kernel 2a: h = pooled @ w1.T + b1, then BatchNorm(batch stats) + ReLU.
// 64 blocks (one per reduced-dim r), 256 threads. Thread t: n = t&15,
// k-slice = t>>4 (32 k's). All loads issued as independent float4s (one
// waitcnt); LDS partial reduce; BN via 16-lane shuffle. Writes hbn[r][n].
// ---------------------------------------------------------------------------
__global__ void __launch_bounds__(256) mlp_h_kernel(
    const float* __restrict__ pooled,   // [16][512]
    const float* __restrict__ w1,       // [64][512]
    const float* __restrict__ b1,
    const float* __restrict__ gamma,
    const float* __restrict__ beta,
    float* __restrict__ hbn)            // [64][16]
{
    const int r = blockIdx.x;
    const int t = threadIdx.x;
    const int n = t & 15;
    const int slice = t >> 4;
    const float4* w1r = reinterpret_cast<const float4*>(w1 + r * Ww + slice * 32);
    const float4* pn  = reinterpret_cast<const float4*>(pooled + n * Ww + slice * 32);

    float acc = 0.f;
    #pragma unroll
    for (int j = 0; j < 8; ++j) {
        const float4 a = w1r[j];
        const float4 p = pn[j];
        acc += a.x * p.x + a.y * p.y + a.z * p.z + a.w * p.w;
    }
    __shared__ float part[16][17];
    part[slice][n] = acc;
    __syncthreads();
    if (t < 16) {                        // t == n
        float h = b1[r];
        #pragma unroll
        for (int s = 0; s < 16; ++s) h += part[s][t];
        float sum = h, sq = h * h;
        #pragma unroll
        for (int off = 1; off < 16; off <<= 1) {
            sum += __shfl_xor(sum, off, 64);
            sq  += __shfl_xor(sq,  off, 64);
        }
        const float mu  = sum * (1.f / 16.f);
        const float var = sq  * (1.f / 16.f) - mu * mu;
        const float is  = 1.f / sqrtf(var + 1e-5f);
        const float v   = gamma[r] * (h - mu) * is + beta[r];
        hbn[r * Nn + t] = fmaxf(v, 0.f);
    }
}

// ---------------------------------------------------------------------------
// Kernel 2b: logits[row][w] = hbn[:,row] . w2[w,:] + b2[w]; rank-based
// top-128 (softmax skipped: monotone). Tie-break matches jax.lax.top_k
// (value desc, index asc); rank-select emits indices already sorted.
// 16 blocks x 512 threads; w2 row preloaded to regs (one waitcnt).
// ---------------------------------------------------------------------------
__global__ void __launch_bounds__(512) logits_topk_kernel(
    const float* __restrict__ hbn,      // [64][16]
    const float* __restrict__ w2,       // [512][64]
    const float* __restrict__ b2,
    int* __restrict__ idx_out)          // [16][128]
{
    const int row = blockIdx.x;
    const int w = threadIdx.x;

    __shared__ float hrow[RED];
    __shared__ float logits_row[Ww];
    __shared__ unsigned long long sel_mask[Ww / 64];

    float4 wv[16];
    const float4* w2r = reinterpret_cast<const float4*>(w2 + w * RED);
    #pragma unroll
    for (int j = 0; j < 16; ++j) wv[j] = w2r[j];
    if (w < RED) hrow[w] = hbn[w * Nn + row];
    __syncthreads();

    float acc = b2[w];
    #pragma unroll
    for (int j = 0; j < 16; ++j) {
        acc += wv[j].x * hrow[j * 4]     + wv[j].y * hrow[j * 4 + 1]
             + wv[j].z * hrow[j * 4 + 2] + wv[j].w * hrow[j * 4 + 3];
    }
    logits_row[w] = acc;
    __syncthreads();

    const float v = logits_row[w];
    int rank = 0;
    for (int ww = 0; ww < Ww; ++ww) {
        const float u = logits_row[ww];
        rank += (u > v || (u == v && ww < w)) ? 1 : 0;
    }
    const bool sel = (rank < OUTW);
    const unsigned long long m = __ballot(sel);
    if ((w & 63) == 0) sel_mask[w >> 6] = m;
    __syncthreads();
    if (sel) {
        int pos = 0;
        #pragma unroll
        for (int bb = 0; bb < (Ww / 64); ++bb)
            if (bb < (w >> 6)) pos += __popcll(sel_mask[bb]);
        pos += __popcll(sel_mask[w >> 6] & ((1ULL << (w & 63)) - 1ULL));
        idx_out[row * OUTW + pos] = w;
    }
}

// ---------------------------------------------------------------------------
// Kernel 3: out[n][c][j][h] = x[n][c][idx[n][j]][h]
// Block b=(n,c): 128 sorted rows read from one contiguous 1MB plane; one
// fully contiguous 256KB write slab. (R3 structure.)
// ---------------------------------------------------------------------------
__global__ void __launch_bounds__(256) gather_kernel(const float* __restrict__ x,
                                                     const int* __restrict__ idx,
                                                     float* __restrict__ out) {
    const int b = blockIdx.x;                 // n*64 + c
    const int n = b >> 6;
    const int tid = threadIdx.x;
    __shared__ int sidx[OUTW];
    if (tid < OUTW) sidx[tid] = idx[n * OUTW + tid];
    __syncthreads();
    const float* src = x   + (size_t)b * (Ww * Hh);
    float*       dst = out + (size_t)b * (OUTW * Hh);
    #pragma unroll 4
    for (int i = tid; i < OUTW * (Hh / 4); i += 256) {
        const int j = i >> 7;
        const int f = i & 127;
        const float4 v = *reinterpret_cast<const float4*>(src + (size_t)sidx[j] * Hh + f * 4);
        *reinterpret_cast<float4*>(dst + (size_t)j * Hh + f * 4) = v;
    }
}

// ---------------------------------------------------------------------------
extern "C" void kernel_launch(void* const* d_in, const int* in_sizes, int n_in,
                              void* d_out, int out_size, void* d_ws, size_t ws_size,
                              hipStream_t stream) {
    const float* x     = (const float*)d_in[0];
    const float* w1    = (const float*)d_in[1];
    const float* b1    = (const float*)d_in[2];
    const float* gamma = (const float*)d_in[3];
    const float* beta  = (const float*)d_in[4];
    const float* w2    = (const float*)d_in[5];
    const float* b2    = (const float*)d_in[6];
    float* out = (float*)d_out;

    float* pooled = (float*)d_ws;                                    // 32 KB
    float* hbn    = (float*)((char*)d_ws + 32768);                   //  4 KB
    int*   idx    = (int*)((char*)d_ws + 32768 + 4096);              //  8 KB

    pool_kernel<<<Nn * (Ww / 4), 256, 0, stream>>>(x, pooled);
    mlp_h_kernel<<<RED, 256, 0, stream>>>(pooled, w1, b1, gamma, beta, hbn);
    logits_topk_kernel<<<Nn, 512, 0, stream>>>(hbn, w2, b2, idx);
    gather_kernel<<<Nn * Cc, 256, 0, stream>>>(x, idx, out);
}